// Round 7
// baseline (305.461 us; speedup 1.0000x reference)
//
#include <hip/hip_runtime.h>
#include <hip/hip_fp8.h>
#include <hip/hip_cooperative_groups.h>
#include <stdint.h>

namespace cg = cooperative_groups;

typedef unsigned short u16;
typedef unsigned char u8;
typedef __attribute__((ext_vector_type(8))) __bf16 bf16x8;
typedef __attribute__((ext_vector_type(8))) short short8s;
typedef __attribute__((ext_vector_type(4))) float float4v;
typedef __attribute__((ext_vector_type(16))) float floatx16;
typedef __attribute__((ext_vector_type(4))) int int4v;
typedef __attribute__((ext_vector_type(8))) int int8v;

// ---------- sizes ----------
static constexpr int NB = 4, NC = 256, NH = 64, NW = 64, NHW = 4096;
static constexpr int BC = 64;        // kv tile (one K=64 PV window per barrier region)
static constexpr int NKV = 4;        // kv split factor
static constexpr int KVCHUNK = NHW / NKV;   // 1024

// ---------- workspace layout (lifetime-aliased) ----------
static constexpr size_t MB = 1ull << 20;
static constexpr size_t OFF_KBF    = 0;          // bf16 [B][C][N] 8MB (dead after mid)
static constexpr size_t OFF_LBF    = 8 * MB;     // bf16 [B][C][N] 8MB (dead after mid)
static constexpr size_t OFF_XT     = 16 * MB;    // bf16 [B][N][C] 8MB (dead after mid)
static constexpr size_t OFF_LPART  = 16 * MB;    // fp32 [B][NKV][N] 256KB — overlays dead xT;
                                                 // consumed by gemm_tail2 phase 0
static constexpr size_t OFF_QT8    = 24 * MB;    // fp8 [B][N][C] 4MB
static constexpr size_t OFF_KT8    = 32 * MB;    // fp8 [B][N][C] 4MB
static constexpr size_t OFF_V8     = 40 * MB;    // fp8 [B][C][N] 4MB
static constexpr size_t OFF_LT     = 48 * MB;    // bf16 [B][N][C] 8MB (localT)
static constexpr size_t OFF_OPART  = 56 * MB;    // fp8 [B][NKV][N][C] 16MB
static constexpr size_t OFF_HIDT   = 88 * MB;    // bf16 [B][N][64] 2MB
static constexpr size_t OFF_GAP    = OFF_HIDT + 2 * MB;        // fp32 [B][256]
static constexpr size_t OFF_WQB    = OFF_GAP + 8 * 1024;       // bf16 256x256
static constexpr size_t OFF_WS1B   = OFF_WQB + 131072;         // bf16 64x256
static constexpr size_t OFF_WS2B   = OFF_WS1B + 32768;         // bf16 256x64
static constexpr size_t OFF_WOB    = OFF_WS2B + 32768;         // bf16 256x256

__device__ __forceinline__ float b2f(u16 h) {
    union { float f; unsigned u; } v; v.u = ((unsigned)h) << 16; return v.f;
}
__device__ __forceinline__ u16 f2b(float f) {
    union { float f; unsigned u; } v; v.f = f;
    unsigned r = v.u + 0x7fffu + ((v.u >> 16) & 1u);
    return (u16)(r >> 16);
}
__device__ __forceinline__ u8 f2f8(float f) {
    __hip_fp8_e4m3 h(f);
    return *reinterpret_cast<u8*>(&h);
}

// async global->LDS, 16B per lane; ldst wave-uniform (HW adds lane*16)
__device__ __forceinline__ void load_lds16(const void* gsrc, void* ldst) {
    __builtin_amdgcn_global_load_lds(
        (__attribute__((address_space(1))) void*)(uintptr_t)gsrc,
        (__attribute__((address_space(3))) void*)ldst,
        16, 0, 0);
}

// ---------- prep mega-kernel: weights+gap | dw k/v(fp8)/local | x transpose ----------
__global__ __launch_bounds__(256) void prep(
    const float* __restrict__ x,
    const float* __restrict__ Wq, const float* __restrict__ Ws1,
    const float* __restrict__ Ws2, const float* __restrict__ Wo,
    const float* __restrict__ Wk, const float* __restrict__ bk,
    const float* __restrict__ Wv, const float* __restrict__ bv,
    const float* __restrict__ Wl, const float* __restrict__ bl,
    u16* __restrict__ Wqb, u16* __restrict__ Ws1b, u16* __restrict__ Ws2b, u16* __restrict__ Wob,
    float* __restrict__ gap,
    u16* __restrict__ k_bf, u8* __restrict__ vN8, u16* __restrict__ local_bf,
    u16* __restrict__ xT)
{
    __shared__ __align__(16) unsigned char pshm[9216];
    const int bid = blockIdx.x;
    const int t = threadIdx.x;

    if (bid < 644) {
        int id = bid * 256 + t;
        if (id < 65536)        Wqb[id] = f2b(Wq[id]);
        else if (id < 81920)   Ws1b[id - 65536] = f2b(Ws1[id - 65536]);
        else if (id < 98304)   Ws2b[id - 81920] = f2b(Ws2[id - 81920]);
        else if (id < 163840)  Wob[id - 98304] = f2b(Wo[id - 98304]);
        else if (id < 164864)  gap[id - 163840] = 0.f;
        return;
    }
    if (bid < 2692) {
        // ---- depthwise k, v, local: register row pipeline, col-neighbors via shuffle ----
        int l = bid - 644;
        int xx0 = t & 63, cl = t >> 6;
        int y0 = (l & 7) * 8;
        int c  = ((l >> 3) & 63) * 4 + cl;
        int b  = l >> 9;
        const float* xb = x + ((size_t)b * NC + c) * NHW;
        float wk[9], wv[9], wl[9];
#pragma unroll
        for (int i = 0; i < 9; i++) { wk[i] = Wk[c*9+i]; wv[i] = Wv[c*9+i]; wl[i] = Wl[c*9+i]; }
        float bkc = bk[c], bvc = bv[c], blc = bl[c];

        auto ldx = [&](int y) -> float {
            return ((unsigned)y <= 63u) ? xb[y * 64 + xx0] : 0.f;
        };
        auto conv3 = [&](const float* w9, float a, float bm, float cc) -> float {
            float au = __shfl_up(a, 1, 64),   ad = __shfl_down(a, 1, 64);
            float bu = __shfl_up(bm, 1, 64),  bd = __shfl_down(bm, 1, 64);
            float cu = __shfl_up(cc, 1, 64),  cd = __shfl_down(cc, 1, 64);
            float al = (xx0 == 0) ? 0.f : au, ar = (xx0 == 63) ? 0.f : ad;
            float bl_ = (xx0 == 0) ? 0.f : bu, br = (xx0 == 63) ? 0.f : bd;
            float cle = (xx0 == 0) ? 0.f : cu, cr = (xx0 == 63) ? 0.f : cd;
            return w9[0]*al + w9[1]*a  + w9[2]*ar
                 + w9[3]*bl_ + w9[4]*bm + w9[5]*br
                 + w9[6]*cle + w9[7]*cc + w9[8]*cr;
        };

        float xm2 = ldx(y0 - 2), xm1 = ldx(y0 - 1), x0v = ldx(y0), xp1 = ldx(y0 + 1);
        float vm1 = (y0 - 1 >= 0) ? (bvc + conv3(wv, xm2, xm1, x0v)) : 0.f;
        float v0  = bvc + conv3(wv, xm1, x0v, xp1);

        size_t base = ((size_t)b * NC + c) * NHW;
#pragma unroll
        for (int yi = 0; yi < 8; yi++) {
            int y = y0 + yi;
            float xp2 = ldx(y + 2);
            float vp1 = (y + 1 <= 63) ? (bvc + conv3(wv, x0v, xp1, xp2)) : 0.f;
            float kk  = bkc + conv3(wk, xm1, x0v, xp1);
            float ll  = blc + conv3(wl, vm1, v0, vp1);
            size_t o = base + y * 64 + xx0;
            k_bf[o]     = f2b(kk);
            vN8[o]      = f2f8(v0);
            local_bf[o] = f2b(ll);
            xm1 = x0v; x0v = xp1; xp1 = xp2;
            vm1 = v0;  v0 = vp1;
        }
        return;
    }
    {
        // ---- transpose-convert x ----
        u16 (*tile)[72] = reinterpret_cast<u16 (*)[72]>(pshm);
        int l = bid - 2692;
        int n0 = (l & 63) * 64;
        int c0 = ((l >> 6) & 3) * 64;
        int b  = l >> 8;
        const float* src = x + (size_t)b * NC * NHW;
        u16* dst = xT + (size_t)b * NHW * NC;
        int c = t >> 2, nb = (t & 3) * 16;
#pragma unroll
        for (int q = 0; q < 4; q++) {
            float4 v = *(const float4*)(src + (size_t)(c0 + c) * NHW + n0 + nb + q * 4);
            tile[c][nb + q * 4 + 0] = f2b(v.x);
            tile[c][nb + q * 4 + 1] = f2b(v.y);
            tile[c][nb + q * 4 + 2] = f2b(v.z);
            tile[c][nb + q * 4 + 3] = f2b(v.w);
        }
        __syncthreads();
        int cl = t & 63, ng = t >> 6;
#pragma unroll
        for (int j = 0; j < 16; j++) {
            int n = ng * 16 + j;
            dst[(size_t)(n0 + n) * NC + c0 + cl] = tile[cl][n];
        }
    }
}

// ---------- mid: transpose (k->kT8, local->localT) | gemm_q (qT8 = fp8(xT.Wq^T+bq)) ----------
// blocks [0,2048): transpose; [2048,2560): gemm_q
__global__ __launch_bounds__(256) void mid(
    const u16* __restrict__ k_bf, const u16* __restrict__ local_bf,
    u8* __restrict__ kT8, u16* __restrict__ localT,
    const u16* __restrict__ xT, const u16* __restrict__ Wqb, const float* __restrict__ bq,
    u8* __restrict__ qT8)
{
    __shared__ __align__(16) u16 tile[64][72];
    const int t = threadIdx.x;
    const int bid = blockIdx.x;
    if (bid < 2048) {
        int n0 = (bid & 63) * 64, c0 = ((bid >> 6) & 3) * 64;
        int zb = bid >> 8, b = zb >> 1;
        const u16* src = (zb & 1) ? local_bf : k_bf;
        src += (size_t)b * NC * NHW;
        int c = t >> 2, nb = (t & 3) * 16;
        *(short8s*)&tile[c][nb]     = *(const short8s*)(src + (size_t)(c0 + c) * NHW + n0 + nb);
        *(short8s*)&tile[c][nb + 8] = *(const short8s*)(src + (size_t)(c0 + c) * NHW + n0 + nb + 8);
        __syncthreads();
        int cl = t & 63, ng = t >> 6;
        if (zb & 1) {
            u16* dst = localT + (size_t)b * NHW * NC;
#pragma unroll
            for (int j = 0; j < 16; j++) {
                int n = ng * 16 + j;
                dst[(size_t)(n0 + n) * NC + c0 + cl] = tile[cl][n];
            }
        } else {
            u8* dst = kT8 + (size_t)b * NHW * NC;
#pragma unroll
            for (int j = 0; j < 16; j++) {
                int n = ng * 16 + j;
                dst[(size_t)(n0 + n) * NC + c0 + cl] = f2f8(b2f(tile[cl][n]));
            }
        }
        return;
    }
    {
        const int w = t >> 6, lane = t & 63;
        const int lm = lane & 15, quad = lane >> 4;
        const int l = bid - 2048;
        const int b = l >> 7;
        const int s_base = (l & 127) * 32 + (w & 1) * 16;
        const int ch = (w >> 1) * 128;
        const u16* xTb = xT + (size_t)b * NHW * NC;
        u8* qTb = qT8 + (size_t)b * NHW * NC;
        bf16x8 aq[8];
#pragma unroll
        for (int kt = 0; kt < 8; kt++)
            aq[kt] = *(const bf16x8*)(xTb + (size_t)(s_base + lm) * NC + kt * 32 + quad * 8);
        float4v acc[8];
#pragma unroll
        for (int j = 0; j < 8; j++) acc[j] = (float4v){0.f, 0.f, 0.f, 0.f};
#pragma unroll
        for (int kt = 0; kt < 8; kt++) {
#pragma unroll
            for (int j = 0; j < 8; j++) {
                bf16x8 bw = *(const bf16x8*)(Wqb + (size_t)(ch + j * 16 + lm) * 256 + kt * 32 + quad * 8);
                acc[j] = __builtin_amdgcn_mfma_f32_16x16x32_bf16(aq[kt], bw, acc[j], 0, 0, 0);
            }
        }
#pragma unroll
        for (int j = 0; j < 8; j++) {
            int cout = ch + j * 16 + lm;
            float bb = bq[cout];
#pragma unroll
            for (int r = 0; r < 4; r++) {
                int s = s_base + quad * 4 + r;
                qTb[(size_t)s * NC + cout] = f2f8(acc[j][r] + bb);
            }
        }
    }
}

// ---------- staging: K fp8 64-row tile (4 DMA/wave) + V fp8 tile (4 DMA/wave) ----------
// K LDS[n][jj*16..] = K[kv0+n][(jj^(n&15))*16..]  (XOR-16 col swizzle, read-side matched)
// V LDS[c][hh*16..] = V[c][kv0 + (hh^((c>>1)&3))*16..]  (XOR dest-chunk swizzle)
__device__ __forceinline__ void stage_tiles(
    const u8* __restrict__ kb, const u8* __restrict__ vb8, int kv0,
    u8* KlB, u8* VlB, int w, int lane)
{
#pragma unroll
    for (int i = 0; i < 4; i++) {
        int g = (w * 4 + i) * 64 + lane;
        int n = g >> 4, jj = g & 15, cc = jj ^ (n & 15);
        load_lds16(kb + (size_t)(kv0 + n) * NC + cc * 16, KlB + (w * 4 + i) * 1024);
    }
#pragma unroll
    for (int i = 0; i < 4; i++) {
        int g = (w * 4 + i) * 64 + lane;
        int c = g >> 2, hh = g & 3;
        int sc = hh ^ ((c >> 1) & 3);
        load_lds16(vb8 + (size_t)c * NHW + kv0 + sc * 16, VlB + (w * 4 + i) * 1024);
    }
}

// ---------- attn (MX-fp8 K=64 QK + PV, permlane32_swap P exchange) | gemm_hid ----------
// blocks [0,512): attn (combo=blockIdx&15 XCD-local); [512,1024): hid
__global__ __launch_bounds__(256, 2) void attn_hid(
    const u8* __restrict__ qT8, const u8* __restrict__ kT8,
    const u8* __restrict__ vN8, u8* __restrict__ Opart8, float* __restrict__ lpart,
    const u16* __restrict__ localT, const u16* __restrict__ Ws1b, const float* __restrict__ bs1,
    u16* __restrict__ hidT)
{
    __shared__ __align__(16) u8 Kl[2][BC * 256];   // 2 x 16KB fp8
    __shared__ __align__(16) u8 Vl[2][256 * BC];   // 2 x 16KB fp8

    const int t = threadIdx.x;
    const int w = t >> 6, lane = t & 63;

    if (blockIdx.x >= 512) {
        // ---- gemm_hid zone ----
        const int lm = lane & 15, quad = lane >> 4;
        const int l = blockIdx.x - 512;
        const int b = l >> 7;
        const int s_base = (l & 127) * 32 + (w & 1) * 16;
        const int ch = (w >> 1) * 32;
        const u16* lTb = localT + (size_t)b * NHW * NC;
        u16* hTb = hidT + (size_t)b * NHW * 64;
        bf16x8 ah[8];
#pragma unroll
        for (int kt = 0; kt < 8; kt++)
            ah[kt] = *(const bf16x8*)(lTb + (size_t)(s_base + lm) * NC + kt * 32 + quad * 8);
        float4v acc[2];
#pragma unroll
        for (int j = 0; j < 2; j++) acc[j] = (float4v){0.f, 0.f, 0.f, 0.f};
#pragma unroll
        for (int kt = 0; kt < 8; kt++) {
#pragma unroll
            for (int j = 0; j < 2; j++) {
                bf16x8 bw = *(const bf16x8*)(Ws1b + (size_t)(ch + j * 16 + lm) * 256 + kt * 32 + quad * 8);
                acc[j] = __builtin_amdgcn_mfma_f32_16x16x32_bf16(ah[kt], bw, acc[j], 0, 0, 0);
            }
        }
#pragma unroll
        for (int j = 0; j < 2; j++) {
            int h = ch + j * 16 + lm;
            float bb = bs1[h];
#pragma unroll
            for (int r = 0; r < 4; r++) {
                int s = s_base + quad * 4 + r;
                hTb[(size_t)s * 64 + h] = f2b(fmaxf(acc[j][r] + bb, 0.0f));
            }
        }
        return;
    }

    // ---- attention zone ----
    const int combo = blockIdx.x & 15;
    const int b  = combo >> 2;
    const int jc = combo & 3;
    const int n0 = (blockIdx.x >> 4) * 128;
    const int lr = lane & 31, l5 = lane >> 5;
    const int m4 = lr & 15;
    const int scl = (int)0x7F7F7F7F;   // unity e8m0 scale (2^0) in every byte
    // exp(s/16) = 2^(s * log2(e)/16)
    const float EC = 0.0901684400f;

    const u8* qb = qT8 + (size_t)b * NHW * NC;
    const u8* kb = kT8 + (size_t)b * NHW * NC;
    const u8* vb8 = vN8 + (size_t)b * NC * NHW;

    // Q B-operand: lane holds Q[qrow][ks*64 + l5*32 .. +31] (K-contiguous per MX block)
    int8v aqm[4];
    {
        int qrow = n0 + w * 32 + lr;
#pragma unroll
        for (int ks = 0; ks < 4; ks++)
            aqm[ks] = *(const int8v*)(qb + (size_t)qrow * NC + ks * 64 + l5 * 32);
    }

    floatx16 oacc[8];
#pragma unroll
    for (int i = 0; i < 8; i++)
#pragma unroll
        for (int j = 0; j < 16; j++) oacc[i][j] = 0.f;
    float lsum = 0.f;

    const int kvbeg = jc * KVCHUNK;
    stage_tiles(kb, vb8, kvbeg, Kl[0], Vl[0], w, lane);

    int buf = 0;
#pragma unroll 1
    for (int it = 0; it < KVCHUNK / BC; it++) {
        const int nxt = (it + 1 < KVCHUNK / BC) ? (kvbeg + (it + 1) * BC) : kvbeg;
        stage_tiles(kb, vb8, nxt, Kl[buf ^ 1], Vl[buf ^ 1], w, lane);
        asm volatile("s_waitcnt vmcnt(8)" ::: "memory");
        __builtin_amdgcn_s_barrier();

        const u8* KlB = Kl[buf];
        const u8* VlB = Vl[buf];

        unsigned uA0, uA1, uA2, uA3, uB0, uB1, uB2, uB3;

        // ---- subtile A (kv 0..31): QK K=64 ×4 + softmax ----
        {
            floatx16 sacc;
#pragma unroll
            for (int j = 0; j < 16; j++) sacc[j] = 0.f;
            __builtin_amdgcn_s_setprio(1);
#pragma unroll
            for (int ks = 0; ks < 4; ks++) {
                int e = ks * 4 + l5 * 2;
                int4v klo = *(const int4v*)&KlB[lr * 256 + ((e ^ m4) * 16)];
                int4v khi = *(const int4v*)&KlB[lr * 256 + (((e + 1) ^ m4) * 16)];
                int8v ka = __builtin_shufflevector(klo, khi, 0, 1, 2, 3, 4, 5, 6, 7);
                sacc = __builtin_amdgcn_mfma_scale_f32_32x32x64_f8f6f4(
                    ka, aqm[ks], sacc, 0, 0, 0, scl, 0, scl);
            }
            __builtin_amdgcn_s_setprio(0);
            float p[16];
#pragma unroll
            for (int r = 0; r < 16; r++)
                p[r] = exp2f(sacc[r] * EC);
            float s0 = (p[0] + p[1]) + (p[2] + p[3]);
            float s1 = (p[4] + p[5]) + (p[6] + p[7]);
            float s2 = (p[8] + p[9]) + (p[10] + p[11]);
            float s3 = (p[12] + p[13]) + (p[14] + p[15]);
            lsum += (s0 + s1) + (s2 + s3);
            uA0 = __builtin_amdgcn_cvt_pk_fp8_f32(p[0], p[1], 0, false);
            uA0 = __builtin_amdgcn_cvt_pk_fp8_f32(p[2], p[3], uA0, true);
            uA1 = __builtin_amdgcn_cvt_pk_fp8_f32(p[4], p[5], 0, false);
            uA1 = __builtin_amdgcn_cvt_pk_fp8_f32(p[6], p[7], uA1, true);
            uA2 = __builtin_amdgcn_cvt_pk_fp8_f32(p[8], p[9], 0, false);
            uA2 = __builtin_amdgcn_cvt_pk_fp8_f32(p[10], p[11], uA2, true);
            uA3 = __builtin_amdgcn_cvt_pk_fp8_f32(p[12], p[13], 0, false);
            uA3 = __builtin_amdgcn_cvt_pk_fp8_f32(p[14], p[15], uA3, true);
        }
        // ---- subtile B (kv 32..63): QK K=64 ×4 + softmax ----
        {
            floatx16 sacc;
#pragma unroll
            for (int j = 0; j < 16; j++) sacc[j] = 0.f;
            __builtin_amdgcn_s_setprio(1);
#pragma unroll
            for (int ks = 0; ks < 4; ks++) {
                int e = ks * 4 + l5 * 2;
                int4v klo = *(const int4v*)&KlB[(32 + lr) * 256 + ((e ^ m4) * 16)];
                int4v khi = *(const int4v*)&KlB[(32 + lr) * 256 + (((e + 1) ^ m4) * 16)];
                int8v ka = __builtin_shufflevector(klo, khi, 0, 1, 2, 3, 4, 5, 6, 7);
                sacc = __builtin_amdgcn_mfma_scale_f32_32x32x64_f8f6f4(
                    ka, aqm[ks], sacc, 0, 0, 0, scl, 0, scl);
            }
            __builtin_amdgcn_s_setprio(0);
            float p[16];
#pragma unroll
            for (int r = 0; r < 16; r++)
                p[r] = exp2f(sacc[r] * EC);
            float s0 = (p[0] + p[1]) + (p[2] + p[3]);
            float s1 = (p[4] + p[5]) + (p[6] + p[7]);
            float s2 = (p[8] + p[9]) + (p[10] + p[11]);
            float s3 = (p[12] + p[13]) + (p[14] + p[15]);
            lsum += (s0 + s1) + (s2 + s3);
            uB0 = __builtin_amdgcn_cvt_pk_fp8_f32(p[0], p[1], 0, false);
            uB0 = __builtin_amdgcn_cvt_pk_fp8_f32(p[2], p[3], uB0, true);
            uB1 = __builtin_amdgcn_cvt_pk_fp8_f32(p[4], p[5], 0, false);
            uB1 = __builtin_amdgcn_cvt_pk_fp8_f32(p[6], p[7], uB1, true);
            uB2 = __builtin_amdgcn_cvt_pk_fp8_f32(p[8], p[9], 0, false);
            uB2 = __builtin_amdgcn_cvt_pk_fp8_f32(p[10], p[11], uB2, true);
            uB3 = __builtin_amdgcn_cvt_pk_fp8_f32(p[12], p[13], 0, false);
            uB3 = __builtin_amdgcn_cvt_pk_fp8_f32(p[14], p[15], uB3, true);
        }
        // ---- P exchange: swap(uA,uB) -> uA' = {uA_lo,uB_lo}, uB' = {uA_hi,uB_hi}
        // A-operand dword d covers kv = l5*32 + 4d + {0..3}: v[2j]=uA_j', v[2j+1]=uB_j'
        asm volatile("v_permlane32_swap_b32 %0, %1" : "+v"(uA0), "+v"(uB0));
        asm volatile("v_permlane32_swap_b32 %0, %1" : "+v"(uA1), "+v"(uB1));
        asm volatile("v_permlane32_swap_b32 %0, %1" : "+v"(uA2), "+v"(uB2));
        asm volatile("v_permlane32_swap_b32 %0, %1" : "+v"(uA3), "+v"(uB3));
        int8v pa = {(int)uA0, (int)uB0, (int)uA1, (int)uB1,
                    (int)uA2, (int)uB2, (int)uA3, (int)uB3};

        // ---- PV: one K=64 MFMA per 32-channel block ----
        __builtin_amdgcn_s_setprio(1);
#pragma unroll
        for (int ct = 0; ct < 8; ct++) {
            int c = ct * 32 + lr;
            int sw = (c >> 1) & 3;
            int4v v0 = *(const int4v*)&VlB[c * 64 + (((l5 * 2) ^ sw) * 16)];
            int4v v1 = *(const int4v*)&VlB[c * 64 + (((l5 * 2 + 1) ^ sw) * 16)];
            int8v bv = __builtin_shufflevector(v0, v1, 0, 1, 2, 3, 4, 5, 6, 7);
            oacc[ct] = __builtin_amdgcn_mfma_scale_f32_32x32x64_f8f6f4(
                pa, bv, oacc[ct], 0, 0, 0, scl, 0, scl);
        }
        __builtin_amdgcn_s_setprio(0);
        __builtin_amdgcn_s_barrier();
        buf ^= 1;
    }

    // epilogue: unnormalized partial O (fp8) + partial l
    lsum += __shfl_xor(lsum, 32, 64);
    u8* Ob = Opart8 + ((size_t)(b * NKV + jc) * NHW + n0 + w * 32) * NC;
#pragma unroll
    for (int reg = 0; reg < 16; reg++) {
        int row = (reg & 3) + 8 * (reg >> 2) + 4 * l5;
#pragma unroll
        for (int ct = 0; ct < 8; ct++)
            Ob[(size_t)row * NC + ct * 32 + lr] = f2f8(oacc[ct][reg]);
    }
    if (lane < 32)
        lpart[(size_t)(b * NKV + jc) * NHW + n0 + w * 32 + lr] = lsum;
}

// ---------- cooperative tail: [combine -> LDS + gap] grid.sync [MLP | sw GEMM | Wo GEMM + residual] ----------
// grid (128 n-tiles, 4 b) = 512 blocks, co-resident (2/CU). gT and fusedT never touch HBM.
__global__ __launch_bounds__(256, 2) void gemm_tail2(
    const u16* __restrict__ hidT, const u16* __restrict__ Ws2b, const float* __restrict__ bs2,
    const u8* __restrict__ Opart8, const float* __restrict__ lpart,
    const u16* __restrict__ localT, float* __restrict__ gap,
    const float* __restrict__ Wc1, const float* __restrict__ bc1,
    const float* __restrict__ Wc2, const float* __restrict__ bc2,
    const u16* __restrict__ Wob, const float* __restrict__ bo,
    const float* __restrict__ x, float* __restrict__ out)
{
    __shared__ float g[256], h1[32], cwl[256];
    __shared__ float ph[32][9];
    __shared__ float gsum[256];
    __shared__ __align__(16) u16 gsl[32][264];   // normalized global_out tile (bf16)
    __shared__ __align__(16) u16 fsh[32][264];   // fused tile
    const int t = threadIdx.x, w = t >> 6, lane = t & 63;
    const int lm = lane & 15, quad = lane >> 4;
    const int b = blockIdx.y;
    const int n_base0 = blockIdx.x * 32;

    // ---- phase 0: combine this block's 32 rows (Opart8 -> gsl) + gap partial ----
    gsum[t] = 0.f;
    __syncthreads();
    {
        int rr = t >> 5;            // 0..7
        int c0 = (t & 31) * 8;
#pragma unroll 1
        for (int itr = 0; itr < 4; itr++) {
            int n = n_base0 + itr * 8 + rr;
            float acc[8] = {};
            float l = 0.f;
#pragma unroll
            for (int j = 0; j < NKV; j++) {
                const u8* op = Opart8 + ((size_t)(b * NKV + j) * NHW + n) * NC + c0;
                unsigned long long v = *(const unsigned long long*)op;
                unsigned lo = (unsigned)v, hi = (unsigned)(v >> 32);
                acc[0] += __builtin_amdgcn_cvt_f32_fp8(lo, 0);
                acc[1] += __builtin_amdgcn_cvt_f32_fp8(lo, 1);
                acc[2] += __builtin_amdgcn_cvt_f32_fp8(lo, 2);
                acc[3] += __builtin_amdgcn_cvt_f32_fp8(lo, 3);
                acc[4] += __builtin_amdgcn_cvt_f32_fp8(hi, 0);
                acc[5] += __builtin_amdgcn_cvt_f32_fp8(hi, 1);
                acc[6] += __builtin_amdgcn_cvt_f32_fp8(hi, 2);
                acc[7] += __builtin_amdgcn_cvt_f32_fp8(hi, 3);
                l += lpart[(size_t)(b * NKV + j) * NHW + n];
            }
            float inv = 1.0f / l;
#pragma unroll
            for (int i = 0; i < 8; i++) acc[i] *= inv;
#pragma unroll
            for (int i = 0; i < 8; i++) gsl[itr * 8 + rr][c0 + i] = f2b(acc[i]);
#pragma unroll
            for (int i = 0; i < 8; i++) atomicAdd(&gsum[c0 + i], acc[i]);
        }
    }
    __syncthreads();
    atomicAdd(&gap[b * NC + t], gsum[t]);

    // ---- all blocks' gap contributions must land before the MLP ----
    cg::this_grid().sync();

    // ---- channel MLP ----
    g[t] = gap[b * 256 + t] * (1.0f / 4096.0f);
    __syncthreads();
    {
        int h = t & 31, part = t >> 5;
        float s = 0.f;
        for (int c = part * 32; c < part * 32 + 32; c++) s += Wc1[h * 256 + c] * g[c];
        ph[h][part] = s;
    }
    __syncthreads();
    if (t < 32) {
        float s = bc1[t];
#pragma unroll
        for (int p = 0; p < 8; p++) s += ph[t][p];
        h1[t] = fmaxf(s, 0.f);
    }
    __syncthreads();
    {
        float s = bc2[t];
#pragma unroll
        for (int j = 0; j < 32; j++) s += Wc2[t * 32 + j] * h1[j];
        cwl[t] = 1.0f / (1.0f + __expf(-s));
    }
    __syncthreads();

    // ---- phase A: fused tile -> LDS (32 n-rows x 256 c) ----
    const int s_base = blockIdx.x * 32 + (w & 1) * 16;
    const int ch = (w >> 1) * 128;
    const u16* hTb = hidT + (size_t)b * NHW * 64;
    const u16* lTb = localT + (size_t)b * NHW * NC;

    {
        bf16x8 ah[2];
#pragma unroll
        for (int kt = 0; kt < 2; kt++)
            ah[kt] = *(const bf16x8*)(hTb + (size_t)(s_base + lm) * 64 + kt * 32 + quad * 8);

        float4v acc[8];
#pragma unroll
        for (int j = 0; j < 8; j++) acc[j] = (float4v){0.f, 0.f, 0.f, 0.f};

#pragma unroll
        for (int kt = 0; kt < 2; kt++) {
#pragma unroll
            for (int j = 0; j < 8; j++) {
                bf16x8 bw = *(const bf16x8*)(Ws2b + (size_t)(ch + j * 16 + lm) * 64 + kt * 32 + quad * 8);
                acc[j] = __builtin_amdgcn_mfma_f32_16x16x32_bf16(ah[kt], bw, acc[j], 0, 0, 0);
            }
        }
#pragma unroll
        for (int j = 0; j < 8; j++) {
            int c = ch + j * 16 + lm;
            float bb = bs2[c];
            float cwv = cwl[c];
#pragma unroll
            for (int r = 0; r < 4; r++) {
                int s = s_base + quad * 4 + r;
                int srow = (w & 1) * 16 + quad * 4 + r;
                float sw = 1.0f / (1.0f + __expf(-(acc[j][r] + bb)));
                float gg = b2f(gsl[srow][c]);
                float lo = b2f(lTb[(size_t)s * NC + c]);
                fsh[srow][c] = f2b(gg * cwv + lo * sw);
            }
        }
    }
    __syncthreads();

    // ---- phase B: out[o][n] = Wo[o][:] . fused[n][:] + bo + x, per wave o-range 64 ----
    {
        const int n_glob = blockIdx.x * 32;
        const int o_base = w * 64;
        float4v acc[4][2];
#pragma unroll
        for (int oj = 0; oj < 4; oj++)
#pragma unroll
            for (int nj = 0; nj < 2; nj++) acc[oj][nj] = (float4v){0.f, 0.f, 0.f, 0.f};

#pragma unroll
        for (int kt = 0; kt < 8; kt++) {
#pragma unroll
            for (int oj = 0; oj < 4; oj++) {
                bf16x8 aw = *(const bf16x8*)(Wob + (size_t)(o_base + oj * 16 + lm) * 256 + kt * 32 + quad * 8);
#pragma unroll
                for (int nj = 0; nj < 2; nj++) {
                    bf16x8 bf = *(const bf16x8*)&fsh[nj * 16 + lm][kt * 32 + quad * 8];
                    acc[oj][nj] = __builtin_amdgcn_mfma_f32_16x16x32_bf16(aw, bf, acc[oj][nj], 0, 0, 0);
                }
            }
        }
#pragma unroll
        for (int oj = 0; oj < 4; oj++) {
#pragma unroll
            for (int r = 0; r < 4; r++) {
                int o = o_base + oj * 16 + quad * 4 + r;
                float bb = bo[o];
                size_t rowoff = ((size_t)b * NC + o) * NHW;
#pragma unroll
                for (int nj = 0; nj < 2; nj++) {
                    int n = n_glob + nj * 16 + lm;
                    out[rowoff + n] = acc[oj][nj][r] + bb + x[rowoff + n];
                }
            }
        }
    }
}

extern "C" void kernel_launch(void* const* d_in, const int* in_sizes, int n_in,
                              void* d_out, int out_size, void* d_ws, size_t ws_size,
                              hipStream_t stream)
{
    const float* x   = (const float*)d_in[0];
    const float* Wq  = (const float*)d_in[1];
    const float* bq  = (const float*)d_in[2];
    const float* Wk  = (const float*)d_in[3];
    const float* bk  = (const float*)d_in[4];
    const float* Wv  = (const float*)d_in[5];
    const float* bv  = (const float*)d_in[6];
    const float* Wl  = (const float*)d_in[7];
    const float* bl  = (const float*)d_in[8];
    const float* Ws1 = (const float*)d_in[9];
    const float* bs1 = (const float*)d_in[10];
    const float* Ws2 = (const float*)d_in[11];
    const float* bs2 = (const float*)d_in[12];
    const float* Wc1 = (const float*)d_in[13];
    const float* bc1 = (const float*)d_in[14];
    const float* Wc2 = (const float*)d_in[15];
    const float* bc2 = (const float*)d_in[16];
    const float* Wo  = (const float*)d_in[17];
    const float* bo  = (const float*)d_in[18];
    float* out = (float*)d_out;

    char* ws = (char*)d_ws;
    u16* k_bf     = (u16*)(ws + OFF_KBF);
    u16* local_bf = (u16*)(ws + OFF_LBF);
    u16* xT       = (u16*)(ws + OFF_XT);
    u8*  qT8      = (u8*)(ws + OFF_QT8);
    u8*  kT8      = (u8*)(ws + OFF_KT8);
    u8*  vN8      = (u8*)(ws + OFF_V8);
    u16* localT   = (u16*)(ws + OFF_LT);
    u8*  Opart8   = (u8*)(ws + OFF_OPART);
    float* lpart  = (float*)(ws + OFF_LPART);
    u16* hidT     = (u16*)(ws + OFF_HIDT);
    float* gap    = (float*)(ws + OFF_GAP);
    u16* Wqb      = (u16*)(ws + OFF_WQB);
    u16* Ws1b     = (u16*)(ws + OFF_WS1B);
    u16* Ws2b     = (u16*)(ws + OFF_WS2B);
    u16* Wob      = (u16*)(ws + OFF_WOB);

    prep<<<dim3(3716), 256, 0, stream>>>(x, Wq, Ws1, Ws2, Wo, Wk, bk, Wv, bv, Wl, bl,
                                         Wqb, Ws1b, Ws2b, Wob, gap, k_bf, vN8, local_bf, xT);
    mid<<<dim3(2560), 256, 0, stream>>>(k_bf, local_bf, kT8, localT, xT, Wqb, bq, qT8);
    attn_hid<<<dim3(1024), 256, 0, stream>>>(qT8, kT8, vN8, Opart8, lpart,
                                             localT, Ws1b, bs1, hidT);
    {
        void* args[] = {(void*)&hidT, (void*)&Ws2b, (void*)&bs2, (void*)&Opart8,
                        (void*)&lpart, (void*)&localT, (void*)&gap,
                        (void*)&Wc1, (void*)&bc1, (void*)&Wc2, (void*)&bc2,
                        (void*)&Wob, (void*)&bo, (void*)&x, (void*)&out};
        hipLaunchCooperativeKernel((void*)gemm_tail2, dim3(128, 4), dim3(256),
                                   args, 0, stream);
    }
}

// Round 8
// 246.514 us; speedup vs baseline: 1.2391x; 1.2391x over previous
//
#include <hip/hip_runtime.h>
#include <hip/hip_fp8.h>
#include <stdint.h>

typedef unsigned short u16;
typedef unsigned char u8;
typedef __attribute__((ext_vector_type(8))) __bf16 bf16x8;
typedef __attribute__((ext_vector_type(8))) short short8s;
typedef __attribute__((ext_vector_type(4))) float float4v;
typedef __attribute__((ext_vector_type(16))) float floatx16;
typedef __attribute__((ext_vector_type(4))) int int4v;
typedef __attribute__((ext_vector_type(8))) int int8v;

// ---------- sizes ----------
static constexpr int NB = 4, NC = 256, NH = 64, NW = 64, NHW = 4096;
static constexpr int BC = 64;        // kv tile (one K=64 PV window per barrier region)
static constexpr int NKV = 4;        // kv split factor
static constexpr int KVCHUNK = NHW / NKV;   // 1024

// ---------- workspace layout (lifetime-aliased) ----------
static constexpr size_t MB = 1ull << 20;
static constexpr size_t OFF_KBF    = 0;          // bf16 [B][C][N] 8MB (dead after mid)
static constexpr size_t OFF_LBF    = 8 * MB;     // bf16 [B][C][N] 8MB (dead after mid)
static constexpr size_t OFF_GT     = 0;          // bf16 [B][N][C] 8MB — overlays KBF
static constexpr size_t OFF_XT     = 16 * MB;    // bf16 [B][N][C] 8MB (dead after mid)
static constexpr size_t OFF_LPART  = 16 * MB;    // fp32 [B][NKV][N] 256KB — overlays dead xT;
                                                 // consumed by attn_combine
static constexpr size_t OFF_QT8    = 24 * MB;    // fp8 [B][N][C] 4MB
static constexpr size_t OFF_KT8    = 32 * MB;    // fp8 [B][N][C] 4MB
static constexpr size_t OFF_V8     = 40 * MB;    // fp8 [B][C][N] 4MB
static constexpr size_t OFF_LT     = 48 * MB;    // bf16 [B][N][C] 8MB (localT)
static constexpr size_t OFF_OPART  = 56 * MB;    // fp8 [B][NKV][N][C] 16MB
static constexpr size_t OFF_HIDT   = 88 * MB;    // bf16 [B][N][64] 2MB
static constexpr size_t OFF_GAP    = OFF_HIDT + 2 * MB;        // fp32 [B][256]
static constexpr size_t OFF_WQB    = OFF_GAP + 8 * 1024;       // bf16 256x256
static constexpr size_t OFF_WS1B   = OFF_WQB + 131072;         // bf16 64x256
static constexpr size_t OFF_WS2B   = OFF_WS1B + 32768;         // bf16 256x64
static constexpr size_t OFF_WOB    = OFF_WS2B + 32768;         // bf16 256x256

__device__ __forceinline__ float b2f(u16 h) {
    union { float f; unsigned u; } v; v.u = ((unsigned)h) << 16; return v.f;
}
__device__ __forceinline__ u16 f2b(float f) {
    union { float f; unsigned u; } v; v.f = f;
    unsigned r = v.u + 0x7fffu + ((v.u >> 16) & 1u);
    return (u16)(r >> 16);
}
__device__ __forceinline__ u8 f2f8(float f) {
    __hip_fp8_e4m3 h(f);
    return *reinterpret_cast<u8*>(&h);
}

// async global->LDS, 16B per lane; ldst wave-uniform (HW adds lane*16)
__device__ __forceinline__ void load_lds16(const void* gsrc, void* ldst) {
    __builtin_amdgcn_global_load_lds(
        (__attribute__((address_space(1))) void*)(uintptr_t)gsrc,
        (__attribute__((address_space(3))) void*)ldst,
        16, 0, 0);
}

// ---------- prep mega-kernel: weights+gap | dw k/v(fp8)/local | x transpose ----------
__global__ __launch_bounds__(256) void prep(
    const float* __restrict__ x,
    const float* __restrict__ Wq, const float* __restrict__ Ws1,
    const float* __restrict__ Ws2, const float* __restrict__ Wo,
    const float* __restrict__ Wk, const float* __restrict__ bk,
    const float* __restrict__ Wv, const float* __restrict__ bv,
    const float* __restrict__ Wl, const float* __restrict__ bl,
    u16* __restrict__ Wqb, u16* __restrict__ Ws1b, u16* __restrict__ Ws2b, u16* __restrict__ Wob,
    float* __restrict__ gap,
    u16* __restrict__ k_bf, u8* __restrict__ vN8, u16* __restrict__ local_bf,
    u16* __restrict__ xT)
{
    __shared__ __align__(16) unsigned char pshm[9216];
    const int bid = blockIdx.x;
    const int t = threadIdx.x;

    if (bid < 644) {
        int id = bid * 256 + t;
        if (id < 65536)        Wqb[id] = f2b(Wq[id]);
        else if (id < 81920)   Ws1b[id - 65536] = f2b(Ws1[id - 65536]);
        else if (id < 98304)   Ws2b[id - 81920] = f2b(Ws2[id - 81920]);
        else if (id < 163840)  Wob[id - 98304] = f2b(Wo[id - 98304]);
        else if (id < 164864)  gap[id - 163840] = 0.f;
        return;
    }
    if (bid < 2692) {
        // ---- depthwise k, v, local: register row pipeline, col-neighbors via shuffle ----
        int l = bid - 644;
        int xx0 = t & 63, cl = t >> 6;
        int y0 = (l & 7) * 8;
        int c  = ((l >> 3) & 63) * 4 + cl;
        int b  = l >> 9;
        const float* xb = x + ((size_t)b * NC + c) * NHW;
        float wk[9], wv[9], wl[9];
#pragma unroll
        for (int i = 0; i < 9; i++) { wk[i] = Wk[c*9+i]; wv[i] = Wv[c*9+i]; wl[i] = Wl[c*9+i]; }
        float bkc = bk[c], bvc = bv[c], blc = bl[c];

        auto ldx = [&](int y) -> float {
            return ((unsigned)y <= 63u) ? xb[y * 64 + xx0] : 0.f;
        };
        auto conv3 = [&](const float* w9, float a, float bm, float cc) -> float {
            float au = __shfl_up(a, 1, 64),   ad = __shfl_down(a, 1, 64);
            float bu = __shfl_up(bm, 1, 64),  bd = __shfl_down(bm, 1, 64);
            float cu = __shfl_up(cc, 1, 64),  cd = __shfl_down(cc, 1, 64);
            float al = (xx0 == 0) ? 0.f : au, ar = (xx0 == 63) ? 0.f : ad;
            float bl_ = (xx0 == 0) ? 0.f : bu, br = (xx0 == 63) ? 0.f : bd;
            float cle = (xx0 == 0) ? 0.f : cu, cr = (xx0 == 63) ? 0.f : cd;
            return w9[0]*al + w9[1]*a  + w9[2]*ar
                 + w9[3]*bl_ + w9[4]*bm + w9[5]*br
                 + w9[6]*cle + w9[7]*cc + w9[8]*cr;
        };

        float xm2 = ldx(y0 - 2), xm1 = ldx(y0 - 1), x0v = ldx(y0), xp1 = ldx(y0 + 1);
        float vm1 = (y0 - 1 >= 0) ? (bvc + conv3(wv, xm2, xm1, x0v)) : 0.f;
        float v0  = bvc + conv3(wv, xm1, x0v, xp1);

        size_t base = ((size_t)b * NC + c) * NHW;
#pragma unroll
        for (int yi = 0; yi < 8; yi++) {
            int y = y0 + yi;
            float xp2 = ldx(y + 2);
            float vp1 = (y + 1 <= 63) ? (bvc + conv3(wv, x0v, xp1, xp2)) : 0.f;
            float kk  = bkc + conv3(wk, xm1, x0v, xp1);
            float ll  = blc + conv3(wl, vm1, v0, vp1);
            size_t o = base + y * 64 + xx0;
            k_bf[o]     = f2b(kk);
            vN8[o]      = f2f8(v0);
            local_bf[o] = f2b(ll);
            xm1 = x0v; x0v = xp1; xp1 = xp2;
            vm1 = v0;  v0 = vp1;
        }
        return;
    }
    {
        // ---- transpose-convert x ----
        u16 (*tile)[72] = reinterpret_cast<u16 (*)[72]>(pshm);
        int l = bid - 2692;
        int n0 = (l & 63) * 64;
        int c0 = ((l >> 6) & 3) * 64;
        int b  = l >> 8;
        const float* src = x + (size_t)b * NC * NHW;
        u16* dst = xT + (size_t)b * NHW * NC;
        int c = t >> 2, nb = (t & 3) * 16;
#pragma unroll
        for (int q = 0; q < 4; q++) {
            float4 v = *(const float4*)(src + (size_t)(c0 + c) * NHW + n0 + nb + q * 4);
            tile[c][nb + q * 4 + 0] = f2b(v.x);
            tile[c][nb + q * 4 + 1] = f2b(v.y);
            tile[c][nb + q * 4 + 2] = f2b(v.z);
            tile[c][nb + q * 4 + 3] = f2b(v.w);
        }
        __syncthreads();
        int cl = t & 63, ng = t >> 6;
#pragma unroll
        for (int j = 0; j < 16; j++) {
            int n = ng * 16 + j;
            dst[(size_t)(n0 + n) * NC + c0 + cl] = tile[cl][n];
        }
    }
}

// ---------- mid: transpose (k->kT8, local->localT) | gemm_q (qT8 = fp8(xT.Wq^T+bq)) ----------
// blocks [0,2048): transpose; [2048,2560): gemm_q
__global__ __launch_bounds__(256) void mid(
    const u16* __restrict__ k_bf, const u16* __restrict__ local_bf,
    u8* __restrict__ kT8, u16* __restrict__ localT,
    const u16* __restrict__ xT, const u16* __restrict__ Wqb, const float* __restrict__ bq,
    u8* __restrict__ qT8)
{
    __shared__ __align__(16) u16 tile[64][72];
    const int t = threadIdx.x;
    const int bid = blockIdx.x;
    if (bid < 2048) {
        int n0 = (bid & 63) * 64, c0 = ((bid >> 6) & 3) * 64;
        int zb = bid >> 8, b = zb >> 1;
        const u16* src = (zb & 1) ? local_bf : k_bf;
        src += (size_t)b * NC * NHW;
        int c = t >> 2, nb = (t & 3) * 16;
        *(short8s*)&tile[c][nb]     = *(const short8s*)(src + (size_t)(c0 + c) * NHW + n0 + nb);
        *(short8s*)&tile[c][nb + 8] = *(const short8s*)(src + (size_t)(c0 + c) * NHW + n0 + nb + 8);
        __syncthreads();
        int cl = t & 63, ng = t >> 6;
        if (zb & 1) {
            u16* dst = localT + (size_t)b * NHW * NC;
#pragma unroll
            for (int j = 0; j < 16; j++) {
                int n = ng * 16 + j;
                dst[(size_t)(n0 + n) * NC + c0 + cl] = tile[cl][n];
            }
        } else {
            u8* dst = kT8 + (size_t)b * NHW * NC;
#pragma unroll
            for (int j = 0; j < 16; j++) {
                int n = ng * 16 + j;
                dst[(size_t)(n0 + n) * NC + c0 + cl] = f2f8(b2f(tile[cl][n]));
            }
        }
        return;
    }
    {
        const int w = t >> 6, lane = t & 63;
        const int lm = lane & 15, quad = lane >> 4;
        const int l = bid - 2048;
        const int b = l >> 7;
        const int s_base = (l & 127) * 32 + (w & 1) * 16;
        const int ch = (w >> 1) * 128;
        const u16* xTb = xT + (size_t)b * NHW * NC;
        u8* qTb = qT8 + (size_t)b * NHW * NC;
        bf16x8 aq[8];
#pragma unroll
        for (int kt = 0; kt < 8; kt++)
            aq[kt] = *(const bf16x8*)(xTb + (size_t)(s_base + lm) * NC + kt * 32 + quad * 8);
        float4v acc[8];
#pragma unroll
        for (int j = 0; j < 8; j++) acc[j] = (float4v){0.f, 0.f, 0.f, 0.f};
#pragma unroll
        for (int kt = 0; kt < 8; kt++) {
#pragma unroll
            for (int j = 0; j < 8; j++) {
                bf16x8 bw = *(const bf16x8*)(Wqb + (size_t)(ch + j * 16 + lm) * 256 + kt * 32 + quad * 8);
                acc[j] = __builtin_amdgcn_mfma_f32_16x16x32_bf16(aq[kt], bw, acc[j], 0, 0, 0);
            }
        }
#pragma unroll
        for (int j = 0; j < 8; j++) {
            int cout = ch + j * 16 + lm;
            float bb = bq[cout];
#pragma unroll
            for (int r = 0; r < 4; r++) {
                int s = s_base + quad * 4 + r;
                qTb[(size_t)s * NC + cout] = f2f8(acc[j][r] + bb);
            }
        }
    }
}

// ---------- staging: K fp8 64-row tile (4 DMA/wave) + V fp8 tile (4 DMA/wave) ----------
// K LDS[n][jj*16..] = K[kv0+n][(jj^(n&15))*16..]  (XOR-16 col swizzle, read-side matched)
// V LDS[c][hh*16..] = V[c][kv0 + (hh^((c>>1)&3))*16..]  (XOR dest-chunk swizzle)
__device__ __forceinline__ void stage_tiles(
    const u8* __restrict__ kb, const u8* __restrict__ vb8, int kv0,
    u8* KlB, u8* VlB, int w, int lane)
{
#pragma unroll
    for (int i = 0; i < 4; i++) {
        int g = (w * 4 + i) * 64 + lane;
        int n = g >> 4, jj = g & 15, cc = jj ^ (n & 15);
        load_lds16(kb + (size_t)(kv0 + n) * NC + cc * 16, KlB + (w * 4 + i) * 1024);
    }
#pragma unroll
    for (int i = 0; i < 4; i++) {
        int g = (w * 4 + i) * 64 + lane;
        int c = g >> 2, hh = g & 3;
        int sc = hh ^ ((c >> 1) & 3);
        load_lds16(vb8 + (size_t)c * NHW + kv0 + sc * 16, VlB + (w * 4 + i) * 1024);
    }
}

// ---------- attn (MX-fp8 K=64 QK + PV, permlane32_swap P exchange) | gemm_hid ----------
// blocks [0,512): attn (combo=blockIdx&15 XCD-local); [512,1024): hid
__global__ __launch_bounds__(256, 2) void attn_hid(
    const u8* __restrict__ qT8, const u8* __restrict__ kT8,
    const u8* __restrict__ vN8, u8* __restrict__ Opart8, float* __restrict__ lpart,
    const u16* __restrict__ localT, const u16* __restrict__ Ws1b, const float* __restrict__ bs1,
    u16* __restrict__ hidT)
{
    __shared__ __align__(16) u8 Kl[2][BC * 256];   // 2 x 16KB fp8
    __shared__ __align__(16) u8 Vl[2][256 * BC];   // 2 x 16KB fp8

    const int t = threadIdx.x;
    const int w = t >> 6, lane = t & 63;

    if (blockIdx.x >= 512) {
        // ---- gemm_hid zone ----
        const int lm = lane & 15, quad = lane >> 4;
        const int l = blockIdx.x - 512;
        const int b = l >> 7;
        const int s_base = (l & 127) * 32 + (w & 1) * 16;
        const int ch = (w >> 1) * 32;
        const u16* lTb = localT + (size_t)b * NHW * NC;
        u16* hTb = hidT + (size_t)b * NHW * 64;
        bf16x8 ah[8];
#pragma unroll
        for (int kt = 0; kt < 8; kt++)
            ah[kt] = *(const bf16x8*)(lTb + (size_t)(s_base + lm) * NC + kt * 32 + quad * 8);
        float4v acc[2];
#pragma unroll
        for (int j = 0; j < 2; j++) acc[j] = (float4v){0.f, 0.f, 0.f, 0.f};
#pragma unroll
        for (int kt = 0; kt < 8; kt++) {
#pragma unroll
            for (int j = 0; j < 2; j++) {
                bf16x8 bw = *(const bf16x8*)(Ws1b + (size_t)(ch + j * 16 + lm) * 256 + kt * 32 + quad * 8);
                acc[j] = __builtin_amdgcn_mfma_f32_16x16x32_bf16(ah[kt], bw, acc[j], 0, 0, 0);
            }
        }
#pragma unroll
        for (int j = 0; j < 2; j++) {
            int h = ch + j * 16 + lm;
            float bb = bs1[h];
#pragma unroll
            for (int r = 0; r < 4; r++) {
                int s = s_base + quad * 4 + r;
                hTb[(size_t)s * 64 + h] = f2b(fmaxf(acc[j][r] + bb, 0.0f));
            }
        }
        return;
    }

    // ---- attention zone ----
    const int combo = blockIdx.x & 15;
    const int b  = combo >> 2;
    const int jc = combo & 3;
    const int n0 = (blockIdx.x >> 4) * 128;
    const int lr = lane & 31, l5 = lane >> 5;
    const int m4 = lr & 15;
    const int scl = (int)0x7F7F7F7F;   // unity e8m0 scale (2^0) in every byte
    // exp(s/16) = 2^(s * log2(e)/16)
    const float EC = 0.0901684400f;

    const u8* qb = qT8 + (size_t)b * NHW * NC;
    const u8* kb = kT8 + (size_t)b * NHW * NC;
    const u8* vb8 = vN8 + (size_t)b * NC * NHW;

    // Q B-operand: lane holds Q[qrow][ks*64 + l5*32 .. +31] (K-contiguous per MX block)
    int8v aqm[4];
    {
        int qrow = n0 + w * 32 + lr;
#pragma unroll
        for (int ks = 0; ks < 4; ks++)
            aqm[ks] = *(const int8v*)(qb + (size_t)qrow * NC + ks * 64 + l5 * 32);
    }

    floatx16 oacc[8];
#pragma unroll
    for (int i = 0; i < 8; i++)
#pragma unroll
        for (int j = 0; j < 16; j++) oacc[i][j] = 0.f;
    float lsum = 0.f;

    const int kvbeg = jc * KVCHUNK;
    stage_tiles(kb, vb8, kvbeg, Kl[0], Vl[0], w, lane);

    int buf = 0;
#pragma unroll 1
    for (int it = 0; it < KVCHUNK / BC; it++) {
        const int nxt = (it + 1 < KVCHUNK / BC) ? (kvbeg + (it + 1) * BC) : kvbeg;
        stage_tiles(kb, vb8, nxt, Kl[buf ^ 1], Vl[buf ^ 1], w, lane);
        asm volatile("s_waitcnt vmcnt(8)" ::: "memory");
        __builtin_amdgcn_s_barrier();

        const u8* KlB = Kl[buf];
        const u8* VlB = Vl[buf];

        unsigned uA0, uA1, uA2, uA3, uB0, uB1, uB2, uB3;

        // ---- subtile A (kv 0..31): QK K=64 ×4 + softmax ----
        {
            floatx16 sacc;
#pragma unroll
            for (int j = 0; j < 16; j++) sacc[j] = 0.f;
            __builtin_amdgcn_s_setprio(1);
#pragma unroll
            for (int ks = 0; ks < 4; ks++) {
                int e = ks * 4 + l5 * 2;
                int4v klo = *(const int4v*)&KlB[lr * 256 + ((e ^ m4) * 16)];
                int4v khi = *(const int4v*)&KlB[lr * 256 + (((e + 1) ^ m4) * 16)];
                int8v ka = __builtin_shufflevector(klo, khi, 0, 1, 2, 3, 4, 5, 6, 7);
                sacc = __builtin_amdgcn_mfma_scale_f32_32x32x64_f8f6f4(
                    ka, aqm[ks], sacc, 0, 0, 0, scl, 0, scl);
            }
            __builtin_amdgcn_s_setprio(0);
            float p[16];
#pragma unroll
            for (int r = 0; r < 16; r++)
                p[r] = exp2f(sacc[r] * EC);
            float s0 = (p[0] + p[1]) + (p[2] + p[3]);
            float s1 = (p[4] + p[5]) + (p[6] + p[7]);
            float s2 = (p[8] + p[9]) + (p[10] + p[11]);
            float s3 = (p[12] + p[13]) + (p[14] + p[15]);
            lsum += (s0 + s1) + (s2 + s3);
            uA0 = __builtin_amdgcn_cvt_pk_fp8_f32(p[0], p[1], 0, false);
            uA0 = __builtin_amdgcn_cvt_pk_fp8_f32(p[2], p[3], uA0, true);
            uA1 = __builtin_amdgcn_cvt_pk_fp8_f32(p[4], p[5], 0, false);
            uA1 = __builtin_amdgcn_cvt_pk_fp8_f32(p[6], p[7], uA1, true);
            uA2 = __builtin_amdgcn_cvt_pk_fp8_f32(p[8], p[9], 0, false);
            uA2 = __builtin_amdgcn_cvt_pk_fp8_f32(p[10], p[11], uA2, true);
            uA3 = __builtin_amdgcn_cvt_pk_fp8_f32(p[12], p[13], 0, false);
            uA3 = __builtin_amdgcn_cvt_pk_fp8_f32(p[14], p[15], uA3, true);
        }
        // ---- subtile B (kv 32..63): QK K=64 ×4 + softmax ----
        {
            floatx16 sacc;
#pragma unroll
            for (int j = 0; j < 16; j++) sacc[j] = 0.f;
            __builtin_amdgcn_s_setprio(1);
#pragma unroll
            for (int ks = 0; ks < 4; ks++) {
                int e = ks * 4 + l5 * 2;
                int4v klo = *(const int4v*)&KlB[(32 + lr) * 256 + ((e ^ m4) * 16)];
                int4v khi = *(const int4v*)&KlB[(32 + lr) * 256 + (((e + 1) ^ m4) * 16)];
                int8v ka = __builtin_shufflevector(klo, khi, 0, 1, 2, 3, 4, 5, 6, 7);
                sacc = __builtin_amdgcn_mfma_scale_f32_32x32x64_f8f6f4(
                    ka, aqm[ks], sacc, 0, 0, 0, scl, 0, scl);
            }
            __builtin_amdgcn_s_setprio(0);
            float p[16];
#pragma unroll
            for (int r = 0; r < 16; r++)
                p[r] = exp2f(sacc[r] * EC);
            float s0 = (p[0] + p[1]) + (p[2] + p[3]);
            float s1 = (p[4] + p[5]) + (p[6] + p[7]);
            float s2 = (p[8] + p[9]) + (p[10] + p[11]);
            float s3 = (p[12] + p[13]) + (p[14] + p[15]);
            lsum += (s0 + s1) + (s2 + s3);
            uB0 = __builtin_amdgcn_cvt_pk_fp8_f32(p[0], p[1], 0, false);
            uB0 = __builtin_amdgcn_cvt_pk_fp8_f32(p[2], p[3], uB0, true);
            uB1 = __builtin_amdgcn_cvt_pk_fp8_f32(p[4], p[5], 0, false);
            uB1 = __builtin_amdgcn_cvt_pk_fp8_f32(p[6], p[7], uB1, true);
            uB2 = __builtin_amdgcn_cvt_pk_fp8_f32(p[8], p[9], 0, false);
            uB2 = __builtin_amdgcn_cvt_pk_fp8_f32(p[10], p[11], uB2, true);
            uB3 = __builtin_amdgcn_cvt_pk_fp8_f32(p[12], p[13], 0, false);
            uB3 = __builtin_amdgcn_cvt_pk_fp8_f32(p[14], p[15], uB3, true);
        }
        // ---- P exchange: swap(uA,uB) -> uA' = {uA_lo,uB_lo}, uB' = {uA_hi,uB_hi}
        // A-operand dword d covers kv = l5*32 + 4d + {0..3}: v[2j]=uA_j', v[2j+1]=uB_j'
        asm volatile("v_permlane32_swap_b32 %0, %1" : "+v"(uA0), "+v"(uB0));
        asm volatile("v_permlane32_swap_b32 %0, %1" : "+v"(uA1), "+v"(uB1));
        asm volatile("v_permlane32_swap_b32 %0, %1" : "+v"(uA2), "+v"(uB2));
        asm volatile("v_permlane32_swap_b32 %0, %1" : "+v"(uA3), "+v"(uB3));
        int8v pa = {(int)uA0, (int)uB0, (int)uA1, (int)uB1,
                    (int)uA2, (int)uB2, (int)uA3, (int)uB3};

        // ---- PV: one K=64 MFMA per 32-channel block ----
        __builtin_amdgcn_s_setprio(1);
#pragma unroll
        for (int ct = 0; ct < 8; ct++) {
            int c = ct * 32 + lr;
            int sw = (c >> 1) & 3;
            int4v v0 = *(const int4v*)&VlB[c * 64 + (((l5 * 2) ^ sw) * 16)];
            int4v v1 = *(const int4v*)&VlB[c * 64 + (((l5 * 2 + 1) ^ sw) * 16)];
            int8v bv = __builtin_shufflevector(v0, v1, 0, 1, 2, 3, 4, 5, 6, 7);
            oacc[ct] = __builtin_amdgcn_mfma_scale_f32_32x32x64_f8f6f4(
                pa, bv, oacc[ct], 0, 0, 0, scl, 0, scl);
        }
        __builtin_amdgcn_s_setprio(0);
        __builtin_amdgcn_s_barrier();
        buf ^= 1;
    }

    // epilogue: unnormalized partial O (fp8) + partial l
    lsum += __shfl_xor(lsum, 32, 64);
    u8* Ob = Opart8 + ((size_t)(b * NKV + jc) * NHW + n0 + w * 32) * NC;
#pragma unroll
    for (int reg = 0; reg < 16; reg++) {
        int row = (reg & 3) + 8 * (reg >> 2) + 4 * l5;
#pragma unroll
        for (int ct = 0; ct < 8; ct++)
            Ob[(size_t)row * NC + ct * 32 + lr] = f2f8(oacc[ct][reg]);
    }
    if (lane < 32)
        lpart[(size_t)(b * NKV + jc) * NHW + n0 + w * 32 + lr] = lsum;
}

// ---------- combine kv-split partials (gT bf16) + fused gap reduce ----------
__global__ __launch_bounds__(256) void attn_combine(
    const u8* __restrict__ Opart8, const float* __restrict__ lpart,
    u16* __restrict__ gT, float* __restrict__ gap)
{
    __shared__ float gsum[256];
    int t = threadIdx.x;
    gsum[t] = 0.f;
    __syncthreads();
    int b = blockIdx.y;
    int n = blockIdx.x * 8 + (t >> 5);
    int c0 = (t & 31) * 8;
    float acc[8] = {};
    float l = 0.f;
#pragma unroll
    for (int j = 0; j < NKV; j++) {
        const u8* op = Opart8 + ((size_t)(b * NKV + j) * NHW + n) * NC + c0;
        unsigned long long v = *(const unsigned long long*)op;
        unsigned lo = (unsigned)v, hi = (unsigned)(v >> 32);
        acc[0] += __builtin_amdgcn_cvt_f32_fp8(lo, 0);
        acc[1] += __builtin_amdgcn_cvt_f32_fp8(lo, 1);
        acc[2] += __builtin_amdgcn_cvt_f32_fp8(lo, 2);
        acc[3] += __builtin_amdgcn_cvt_f32_fp8(lo, 3);
        acc[4] += __builtin_amdgcn_cvt_f32_fp8(hi, 0);
        acc[5] += __builtin_amdgcn_cvt_f32_fp8(hi, 1);
        acc[6] += __builtin_amdgcn_cvt_f32_fp8(hi, 2);
        acc[7] += __builtin_amdgcn_cvt_f32_fp8(hi, 3);
        l += lpart[(size_t)(b * NKV + j) * NHW + n];
    }
    float inv = 1.0f / l;
#pragma unroll
    for (int i = 0; i < 8; i++) acc[i] *= inv;
    short8s vo;
#pragma unroll
    for (int i = 0; i < 8; i++) ((u16*)&vo)[i] = f2b(acc[i]);
    *(short8s*)(gT + ((size_t)b * NHW + n) * NC + c0) = vo;
#pragma unroll
    for (int i = 0; i < 8; i++) atomicAdd(&gsum[c0 + i], acc[i]);
    __syncthreads();
    atomicAdd(&gap[b * NC + t], gsum[t]);
}

// ---------- fused tail: [channel-MLP + sw GEMM + fuse -> LDS] then [Wo GEMM + residual] ----------
// grid (128 n-tiles, 4 b); block covers 32 n-rows x 256 c. fusedT never touches HBM.
__global__ __launch_bounds__(256) void gemm_tail(
    const u16* __restrict__ hidT, const u16* __restrict__ Ws2b, const float* __restrict__ bs2,
    const u16* __restrict__ gT, const u16* __restrict__ localT,
    const float* __restrict__ gap,
    const float* __restrict__ Wc1, const float* __restrict__ bc1,
    const float* __restrict__ Wc2, const float* __restrict__ bc2,
    const u16* __restrict__ Wob, const float* __restrict__ bo,
    const float* __restrict__ x, float* __restrict__ out)
{
    __shared__ float g[256], h1[32], cwl[256];
    __shared__ float ph[32][9];
    __shared__ __align__(16) u16 fsh[32][264];   // fused tile (row pad 8 u16 -> 528B, bank-safe)
    const int t = threadIdx.x, w = t >> 6, lane = t & 63;
    const int lm = lane & 15, quad = lane >> 4;
    const int b = blockIdx.y;

    g[t] = gap[b * 256 + t] * (1.0f / 4096.0f);
    __syncthreads();
    {
        int h = t & 31, part = t >> 5;
        float s = 0.f;
        for (int c = part * 32; c < part * 32 + 32; c++) s += Wc1[h * 256 + c] * g[c];
        ph[h][part] = s;
    }
    __syncthreads();
    if (t < 32) {
        float s = bc1[t];
#pragma unroll
        for (int p = 0; p < 8; p++) s += ph[t][p];
        h1[t] = fmaxf(s, 0.f);
    }
    __syncthreads();
    {
        float s = bc2[t];
#pragma unroll
        for (int j = 0; j < 32; j++) s += Wc2[t * 32 + j] * h1[j];
        cwl[t] = 1.0f / (1.0f + __expf(-s));
    }
    __syncthreads();

    // ---- phase A: fused tile -> LDS (32 n-rows x 256 c) ----
    const int s_base = blockIdx.x * 32 + (w & 1) * 16;
    const int ch = (w >> 1) * 128;
    const u16* hTb = hidT + (size_t)b * NHW * 64;
    const u16* lTb = localT + (size_t)b * NHW * NC;
    const u16* gTb = gT + (size_t)b * NHW * NC;

    {
        bf16x8 ah[2];
#pragma unroll
        for (int kt = 0; kt < 2; kt++)
            ah[kt] = *(const bf16x8*)(hTb + (size_t)(s_base + lm) * 64 + kt * 32 + quad * 8);

        float4v acc[8];
#pragma unroll
        for (int j = 0; j < 8; j++) acc[j] = (float4v){0.f, 0.f, 0.f, 0.f};

#pragma unroll
        for (int kt = 0; kt < 2; kt++) {
#pragma unroll
            for (int j = 0; j < 8; j++) {
                bf16x8 bw = *(const bf16x8*)(Ws2b + (size_t)(ch + j * 16 + lm) * 64 + kt * 32 + quad * 8);
                acc[j] = __builtin_amdgcn_mfma_f32_16x16x32_bf16(ah[kt], bw, acc[j], 0, 0, 0);
            }
        }
#pragma unroll
        for (int j = 0; j < 8; j++) {
            int c = ch + j * 16 + lm;
            float bb = bs2[c];
            float cwv = cwl[c];
#pragma unroll
            for (int r = 0; r < 4; r++) {
                int s = s_base + quad * 4 + r;
                int srow = (w & 1) * 16 + quad * 4 + r;
                float sw = 1.0f / (1.0f + __expf(-(acc[j][r] + bb)));
                float gg = b2f(gTb[(size_t)s * NC + c]);
                float lo = b2f(lTb[(size_t)s * NC + c]);
                fsh[srow][c] = f2b(gg * cwv + lo * sw);
            }
        }
    }
    __syncthreads();

    // ---- phase B: out[o][n] = Wo[o][:] . fused[n][:] + bo + x, per wave o-range 64 ----
    {
        const int n_glob = blockIdx.x * 32;
        const int o_base = w * 64;
        float4v acc[4][2];
#pragma unroll
        for (int oj = 0; oj < 4; oj++)
#pragma unroll
            for (int nj = 0; nj < 2; nj++) acc[oj][nj] = (float4v){0.f, 0.f, 0.f, 0.f};

#pragma unroll
        for (int kt = 0; kt < 8; kt++) {
#pragma unroll
            for (int oj = 0; oj < 4; oj++) {
                bf16x8 aw = *(const bf16x8*)(Wob + (size_t)(o_base + oj * 16 + lm) * 256 + kt * 32 + quad * 8);
#pragma unroll
                for (int nj = 0; nj < 2; nj++) {
                    bf16x8 bf = *(const bf16x8*)&fsh[nj * 16 + lm][kt * 32 + quad * 8];
                    acc[oj][nj] = __builtin_amdgcn_mfma_f32_16x16x32_bf16(aw, bf, acc[oj][nj], 0, 0, 0);
                }
            }
        }
#pragma unroll
        for (int oj = 0; oj < 4; oj++) {
#pragma unroll
            for (int r = 0; r < 4; r++) {
                int o = o_base + oj * 16 + quad * 4 + r;
                float bb = bo[o];
                size_t rowoff = ((size_t)b * NC + o) * NHW;
#pragma unroll
                for (int nj = 0; nj < 2; nj++) {
                    int n = n_glob + nj * 16 + lm;
                    out[rowoff + n] = acc[oj][nj][r] + bb + x[rowoff + n];
                }
            }
        }
    }
}

extern "C" void kernel_launch(void* const* d_in, const int* in_sizes, int n_in,
                              void* d_out, int out_size, void* d_ws, size_t ws_size,
                              hipStream_t stream)
{
    const float* x   = (const float*)d_in[0];
    const float* Wq  = (const float*)d_in[1];
    const float* bq  = (const float*)d_in[2];
    const float* Wk  = (const float*)d_in[3];
    const float* bk  = (const float*)d_in[4];
    const float* Wv  = (const float*)d_in[5];
    const float* bv  = (const float*)d_in[6];
    const float* Wl  = (const float*)d_in[7];
    const float* bl  = (const float*)d_in[8];
    const float* Ws1 = (const float*)d_in[9];
    const float* bs1 = (const float*)d_in[10];
    const float* Ws2 = (const float*)d_in[11];
    const float* bs2 = (const float*)d_in[12];
    const float* Wc1 = (const float*)d_in[13];
    const float* bc1 = (const float*)d_in[14];
    const float* Wc2 = (const float*)d_in[15];
    const float* bc2 = (const float*)d_in[16];
    const float* Wo  = (const float*)d_in[17];
    const float* bo  = (const float*)d_in[18];
    float* out = (float*)d_out;

    char* ws = (char*)d_ws;
    u16* k_bf     = (u16*)(ws + OFF_KBF);
    u16* local_bf = (u16*)(ws + OFF_LBF);
    u16* gT       = (u16*)(ws + OFF_GT);
    u16* xT       = (u16*)(ws + OFF_XT);
    u8*  qT8      = (u8*)(ws + OFF_QT8);
    u8*  kT8      = (u8*)(ws + OFF_KT8);
    u8*  vN8      = (u8*)(ws + OFF_V8);
    u16* localT   = (u16*)(ws + OFF_LT);
    u8*  Opart8   = (u8*)(ws + OFF_OPART);
    float* lpart  = (float*)(ws + OFF_LPART);
    u16* hidT     = (u16*)(ws + OFF_HIDT);
    float* gap    = (float*)(ws + OFF_GAP);
    u16* Wqb      = (u16*)(ws + OFF_WQB);
    u16* Ws1b     = (u16*)(ws + OFF_WS1B);
    u16* Ws2b     = (u16*)(ws + OFF_WS2B);
    u16* Wob      = (u16*)(ws + OFF_WOB);

    prep<<<dim3(3716), 256, 0, stream>>>(x, Wq, Ws1, Ws2, Wo, Wk, bk, Wv, bv, Wl, bl,
                                         Wqb, Ws1b, Ws2b, Wob, gap, k_bf, vN8, local_bf, xT);
    mid<<<dim3(2560), 256, 0, stream>>>(k_bf, local_bf, kT8, localT, xT, Wqb, bq, qT8);
    attn_hid<<<dim3(1024), 256, 0, stream>>>(qT8, kT8, vN8, Opart8, lpart,
                                             localT, Ws1b, bs1, hidT);
    attn_combine<<<dim3(NHW / 8, 4), 256, 0, stream>>>(Opart8, lpart, gT, gap);
    gemm_tail<<<dim3(128, 4), 256, 0, stream>>>(hidT, Ws2b, bs2, gT, localT,
                                                gap, Wc1, bc1, Wc2, bc2,
                                                Wob, bo, x, out);
}